// Round 10
// baseline (490.560 us; speedup 1.0000x reference)
//
#include <hip/hip_runtime.h>
#include <hip/hip_cooperative_groups.h>
namespace cg = cooperative_groups;

// images=8, patches=3600(=60*60), hor_f=64, ver_f=25(=5*5), 64x64 px, k=5
#define OH     60
#define NIMG   8
#define HF     64
#define VF     25
#define NPATCH 3600
#define CDIM   1600
#define FH     8
#define FC     200
#define SPI    5
#define PJS    64
#define NSTRIP 12
#define SROWS  9
#define NBLK   768
#define LIJ    68                    // li row stride (per-wave unfold tile)
#define LIW    1360                  // 20 rows * 68 floats per wave
#define NUNITS 7680                  // 60 pi * 4 hh * 4 chq * 8 im

// ============================ fused cooperative kernel ========================
__global__ __launch_bounds__(512, 6) void fused_kernel(const float* __restrict__ x,
                                                       float* __restrict__ slab,
                                                       int* __restrict__ cnt,
                                                       float* __restrict__ out) {
    __shared__ float lb[12800];      // fold stage buffer; reused as 8 per-wave li slices
    __shared__ int4 lut25[25];
    const int b = blockIdx.x, t = threadIdx.x;

    if (b == 0 && t < 8) cnt[t] = 0;
    cg::this_grid().sync();

    // ---------------- phase 1: fold (r8 structure) ----------------
    const int hg = b & 7, strip = (b >> 3) % 12, im = b / 96;
    const int h0 = hg * FH;
    const int pi0 = strip * SPI;
    const int j = t & 63, g = t >> 6;

    float acc[SROWS];
#pragma unroll
    for (int k = 0; k < SROWS; ++k) acc[k] = 0.f;

    const float* xb = x + ((size_t)im * NPATCH + (size_t)pi0 * OH) * CDIM + h0 * VF;

    int off_g[6], off_l[6];
#pragma unroll
    for (int k = 0; k < 6; ++k) {
        int u = t + 512 * k;
        if (u < 3000) {
            int pj = u / 50, c4 = u - 50 * pj;
            off_g[k] = pj * CDIM + (c4 << 2);
            off_l[k] = (c4 << 8) + (pj ^ (c4 & 31));
        }
    }

    float4 stg[6];
#pragma unroll
    for (int k = 0; k < 6; ++k)
        if (t + 512 * k < 3000)
            stg[k] = *reinterpret_cast<const float4*>(xb + off_g[k]);

#pragma unroll
    for (int row = 0; row < SPI; ++row) {
        if (row) __syncthreads();
#pragma unroll
        for (int k = 0; k < 6; ++k)
            if (t + 512 * k < 3000) {
                float4 v = stg[k];
                int a = off_l[k];
                lb[a]           = v.x;
                lb[a + PJS]     = v.y;
                lb[a + 2 * PJS] = v.z;
                lb[a + 3 * PJS] = v.w;
            }
        if (row + 1 < SPI) {
#pragma unroll
            for (int k = 0; k < 6; ++k)
                if (t + 512 * k < 3000)
                    stg[k] = *reinterpret_cast<const float4*>(
                        xb + (size_t)(row + 1) * OH * CDIM + off_g[k]);
        }
        __syncthreads();
#pragma unroll
        for (int di = 0; di < 5; ++di) {
#pragma unroll
            for (int dj = 0; dj < 5; ++dj) {
                int c = g * VF + di * 5 + dj;
                int pjr = j - dj;
                if ((unsigned)pjr < 60u)
                    acc[row + di] += lb[c * PJS + (pjr ^ ((c >> 2) & 31))];
            }
        }
    }

    float* sb = slab + (((size_t)(strip * 8 + im) * 64 + h0 + g) * SROWS) * 64 + j;
#pragma unroll
    for (int il = 0; il < SROWS; ++il) sb[il * 64] = acc[il];

    // publish: barrier drains each wave's vmcnt; release-add makes stores visible
    __syncthreads();
    if (t == 0)
        __hip_atomic_fetch_add(cnt + im, 1, __ATOMIC_RELEASE, __HIP_MEMORY_SCOPE_AGENT);
    if (t < 25) {                    // lut: f4-slot r -> 4 li offsets (R*LIJ + dj)
        int4 e;
        int* ep = &e.x;
#pragma unroll
        for (int k = 0; k < 4; ++k) {
            int fl = 4 * t + k;      // = chl*25 + v, fl < 100
            int chl = fl / 25, v = fl - 25 * chl;
            int di = v / 5, dj = v - 5 * di;
            ep[k] = (chl * 5 + di) * LIJ + dj;
        }
        lut25[t] = e;
    }
    __syncthreads();                 // lut visible; lb free for reuse

    // ---------------- phase 2: per-wave unfold units ----------------
    const int wave = t >> 6, lane = t & 63;
    const int wb = wave * LIW;

    for (int u = (b << 3) + wave; u < NUNITS; u += NBLK * 8) {
        const int im2 = u & 7;
        const int q   = u >> 3;
        const int chq = q & 3;
        const int hh  = (q >> 2) & 3;
        const int pi  = q >> 4;              // 0..59
        const int ch0 = hh * 16 + chq * 4;

        if (lane == 0) {
            while (__hip_atomic_load(cnt + im2, __ATOMIC_ACQUIRE,
                                     __HIP_MEMORY_SCOPE_AGENT) < 96)
                __builtin_amdgcn_s_sleep(2);
        }

        // stage: 4 ch x 5 di x 16 j4, strip-summed, pre-scaled by 1/(ci*cj)
        for (int s = lane; s < 320; s += 64) {
            int chl = s / 80, rem = s - 80 * chl;
            int di = rem >> 4, j4 = rem & 15;
            int i = pi + di;
            int s_hi = min(i / 5, NSTRIP - 1);
            int s_lo = (i <= 8) ? 0 : (i - 4) / 5;
            const float* pa = slab +
                (((size_t)(s_lo * 8 + im2) * 64 + ch0 + chl) * SROWS + (i - 5 * s_lo)) * 64 + (j4 << 2);
            float4 v = *reinterpret_cast<const float4*>(pa);
            if (s_hi != s_lo) {
                const float* pb = slab +
                    (((size_t)(s_hi * 8 + im2) * 64 + ch0 + chl) * SROWS + (i - 5 * s_hi)) * 64 + (j4 << 2);
                float4 w2 = *reinterpret_cast<const float4*>(pb);
                v.x += w2.x; v.y += w2.y; v.z += w2.z; v.w += w2.w;
            }
            float ri = 1.0f / (float)min(min(i + 1, 64 - i), 5);
            int jb = j4 << 2;
            float4 w;
            w.x = v.x * ri * (1.0f / (float)min(min(jb + 1, 64 - jb), 5));
            w.y = v.y * ri * (1.0f / (float)min(min(jb + 2, 63 - jb), 5));
            w.z = v.z * ri * (1.0f / (float)min(min(jb + 3, 62 - jb), 5));
            w.w = v.w * ri * (1.0f / (float)min(min(jb + 4, 61 - jb), 5));
            *reinterpret_cast<float4*>(&lb[wb + (chl * 5 + di) * LIJ + jb]) = w;
        }

        // emit: 60 pj x 25 f4 (4 ch x 25 v per pj), 400B runs, coalesced
        float* ob = out + ((size_t)im2 * NPATCH + (size_t)pi * OH) * CDIM + ch0 * VF;
        for (int e = lane; e < 1500; e += 64) {
            int pj = e / 25, r = e - 25 * pj;
            int4 off = lut25[r];
            float4 o;
            o.x = lb[wb + off.x + pj];
            o.y = lb[wb + off.y + pj];
            o.z = lb[wb + off.z + pj];
            o.w = lb[wb + off.w + pj];
            *reinterpret_cast<float4*>(ob + (size_t)pj * CDIM + (r << 2)) = o;
        }
    }
}

// ============================ fallback: r8 two-kernel path ====================
__global__ __launch_bounds__(512, 6) void fold_kernel(const float* __restrict__ x,
                                                      float* __restrict__ slab) {
    __shared__ float lb[FC * PJS];
    const int hg = blockIdx.x, strip = blockIdx.y, im = blockIdx.z;
    const int t = threadIdx.x;
    const int h0 = hg * FH;
    const int pi0 = strip * SPI;
    const int j = t & 63, g = t >> 6;

    float acc[SROWS];
#pragma unroll
    for (int k = 0; k < SROWS; ++k) acc[k] = 0.f;

    const float* xb = x + ((size_t)im * NPATCH + (size_t)pi0 * OH) * CDIM + h0 * VF;

    int off_g[6], off_l[6];
#pragma unroll
    for (int k = 0; k < 6; ++k) {
        int u = t + 512 * k;
        if (u < 3000) {
            int pj = u / 50, c4 = u - 50 * pj;
            off_g[k] = pj * CDIM + (c4 << 2);
            off_l[k] = (c4 << 8) + (pj ^ (c4 & 31));
        }
    }

    float4 stg[6];
#pragma unroll
    for (int k = 0; k < 6; ++k)
        if (t + 512 * k < 3000)
            stg[k] = *reinterpret_cast<const float4*>(xb + off_g[k]);

#pragma unroll
    for (int row = 0; row < SPI; ++row) {
        if (row) __syncthreads();
#pragma unroll
        for (int k = 0; k < 6; ++k)
            if (t + 512 * k < 3000) {
                float4 v = stg[k];
                int a = off_l[k];
                lb[a]           = v.x;
                lb[a + PJS]     = v.y;
                lb[a + 2 * PJS] = v.z;
                lb[a + 3 * PJS] = v.w;
            }
        if (row + 1 < SPI) {
#pragma unroll
            for (int k = 0; k < 6; ++k)
                if (t + 512 * k < 3000)
                    stg[k] = *reinterpret_cast<const float4*>(
                        xb + (size_t)(row + 1) * OH * CDIM + off_g[k]);
        }
        __syncthreads();
#pragma unroll
        for (int di = 0; di < 5; ++di) {
#pragma unroll
            for (int dj = 0; dj < 5; ++dj) {
                int c = g * VF + di * 5 + dj;
                int pjr = j - dj;
                if ((unsigned)pjr < 60u)
                    acc[row + di] += lb[c * PJS + (pjr ^ ((c >> 2) & 31))];
            }
        }
    }

    float* sb = slab + (((size_t)(strip * 8 + im) * 64 + h0 + g) * SROWS) * 64 + j;
#pragma unroll
    for (int il = 0; il < SROWS; ++il) sb[il * 64] = acc[il];
}

#define UH   16
#define LJS  68

__global__ __launch_bounds__(256) void unfold_kernel(const float* __restrict__ slab,
                                                     float* __restrict__ out) {
    __shared__ float li[UH * 5 * LJS];
    __shared__ int4 lut[100];
    const int hh = blockIdx.x;
    const int pi = blockIdx.y;
    const int im = blockIdx.z;
    const int t = threadIdx.x;
    const int h0 = hh * UH;

    if (t < 100) {
        int4 e;
        int* ep = &e.x;
#pragma unroll
        for (int k = 0; k < 4; ++k) {
            int fl = 4 * t + k;
            int ho = fl / 25, v = fl - 25 * ho;
            int di = v / 5, dj = v - 5 * di;
            ep[k] = (ho * 5 + di) * LJS + dj;
        }
        lut[t] = e;
    }

    for (int u = t; u < UH * 5 * 16; u += 256) {
        int ch = u / 80, rem = u - 80 * ch;
        int di = rem >> 4, j4 = rem & 15;
        int i = pi + di;
        int s_hi = min(i / 5, NSTRIP - 1);
        int s_lo = (i <= 8) ? 0 : (i - 4) / 5;
        const float* pa = slab +
            (((size_t)(s_lo * 8 + im) * 64 + h0 + ch) * SROWS + (i - 5 * s_lo)) * 64 + (j4 << 2);
        float4 v = *reinterpret_cast<const float4*>(pa);
        if (s_hi != s_lo) {
            const float* pb = slab +
                (((size_t)(s_hi * 8 + im) * 64 + h0 + ch) * SROWS + (i - 5 * s_hi)) * 64 + (j4 << 2);
            float4 w = *reinterpret_cast<const float4*>(pb);
            v.x += w.x; v.y += w.y; v.z += w.z; v.w += w.w;
        }
        float ri = 1.0f / (float)min(min(i + 1, 64 - i), 5);
        int jb = j4 << 2;
        float4 w;
        w.x = v.x * ri * (1.0f / (float)min(min(jb + 1, 64 - jb), 5));
        w.y = v.y * ri * (1.0f / (float)min(min(jb + 2, 63 - jb), 5));
        w.z = v.z * ri * (1.0f / (float)min(min(jb + 3, 62 - jb), 5));
        w.w = v.w * ri * (1.0f / (float)min(min(jb + 4, 61 - jb), 5));
        *reinterpret_cast<float4*>(&li[(ch * 5 + di) * LJS + jb]) = w;
    }
    __syncthreads();

    float* ob = out + ((size_t)im * NPATCH + (size_t)pi * OH) * CDIM + h0 * VF;
    for (int u = t; u < 6000; u += 256) {
        int pj = u / 100, r = u - 100 * pj;
        int4 e = lut[r];
        float4 o;
        o.x = li[e.x + pj];
        o.y = li[e.y + pj];
        o.z = li[e.z + pj];
        o.w = li[e.w + pj];
        *reinterpret_cast<float4*>(ob + (size_t)pj * CDIM + 4 * r) = o;
    }
}

// ================================= launch =====================================
extern "C" void kernel_launch(void* const* d_in, const int* in_sizes, int n_in,
                              void* d_out, int out_size, void* d_ws, size_t ws_size,
                              hipStream_t stream) {
    const float* x = (const float*)d_in[0];
    float* slab = (float*)d_ws;                          // 3,538,944 floats = 14.16 MB
    int* cnt = (int*)(slab + (size_t)NSTRIP * 8 * 64 * SROWS * 64);  // 8 ints after slab
    float* out = (float*)d_out;

    void* args[] = {(void*)&x, (void*)&slab, (void*)&cnt, (void*)&out};
    hipError_t err = hipLaunchCooperativeKernel((const void*)fused_kernel,
                                                dim3(NBLK), dim3(512), args, 0, stream);
    if (err != hipSuccess) {
        (void)hipGetLastError();                         // clear error state
        fold_kernel<<<dim3(8, NSTRIP, NIMG), 512, 0, stream>>>(x, slab);
        unfold_kernel<<<dim3(4, OH, NIMG), 256, 0, stream>>>(slab, out);
    }
    (void)out_size; (void)ws_size; (void)in_sizes; (void)n_in;
}

// Round 11
// 98.708 us; speedup vs baseline: 4.9698x; 4.9698x over previous
//
#include <hip/hip_runtime.h>

// images=8, patches=3600(=60*60), hor_f=64, ver_f=25(=5*5), 64x64 px, k=5
#define OH     60
#define NIMG   8
#define HF     64
#define VF     25
#define NPATCH 3600
#define CDIM   1600                  // HF*VF

// ---- fold (r8, unchanged): grid (hg 8, strip 12, im 8), 512 threads ----
#define FH   8                       // h channels per block
#define FC   (FH * VF)               // 200 c values
#define SPI  5                       // pi rows per strip
#define PJS  64                      // pj stride (XOR-swizzled)
#define NSTRIP 12
#define SROWS  9                     // SPI + 4 halo rows

__global__ __launch_bounds__(512, 6) void fold_kernel(const float* __restrict__ x,
                                                      float* __restrict__ slab) {
    __shared__ float lb[FC * PJS];   // 51.2 KB
    const int hg = blockIdx.x, strip = blockIdx.y, im = blockIdx.z;
    const int t = threadIdx.x;
    const int h0 = hg * FH;
    const int pi0 = strip * SPI;
    const int j = t & 63, g = t >> 6;          // g = local h (0..7)

    float acc[SROWS];
#pragma unroll
    for (int k = 0; k < SROWS; ++k) acc[k] = 0.f;

    const float* xb = x + ((size_t)im * NPATCH + (size_t)pi0 * OH) * CDIM + h0 * VF;

    int off_g[6], off_l[6];
#pragma unroll
    for (int k = 0; k < 6; ++k) {
        int u = t + 512 * k;
        if (u < 3000) {
            int pj = u / 50, c4 = u - 50 * pj;
            off_g[k] = pj * CDIM + (c4 << 2);
            off_l[k] = (c4 << 8) + (pj ^ (c4 & 31));
        }
    }

    float4 stg[6];
#pragma unroll
    for (int k = 0; k < 6; ++k)
        if (t + 512 * k < 3000)
            stg[k] = *reinterpret_cast<const float4*>(xb + off_g[k]);

#pragma unroll
    for (int row = 0; row < SPI; ++row) {
        if (row) __syncthreads();
#pragma unroll
        for (int k = 0; k < 6; ++k)
            if (t + 512 * k < 3000) {
                float4 v = stg[k];
                int a = off_l[k];
                lb[a]           = v.x;
                lb[a + PJS]     = v.y;
                lb[a + 2 * PJS] = v.z;
                lb[a + 3 * PJS] = v.w;
            }
        if (row + 1 < SPI) {                   // prefetch next row during compute
#pragma unroll
            for (int k = 0; k < 6; ++k)
                if (t + 512 * k < 3000)
                    stg[k] = *reinterpret_cast<const float4*>(
                        xb + (size_t)(row + 1) * OH * CDIM + off_g[k]);
        }
        __syncthreads();
#pragma unroll
        for (int di = 0; di < 5; ++di) {
#pragma unroll
            for (int dj = 0; dj < 5; ++dj) {
                int c = g * VF + di * 5 + dj;
                int pjr = j - dj;
                if ((unsigned)pjr < 60u)
                    acc[row + di] += lb[c * PJS + (pjr ^ ((c >> 2) & 31))];
            }
        }
    }

    float* sb = slab + (((size_t)(strip * 8 + im) * 64 + h0 + g) * SROWS) * 64 + j;
#pragma unroll
    for (int il = 0; il < SROWS; ++il) sb[il * 64] = acc[il];
}

// ---- unfold v4: grid (hh 4, piq 30, im 8) = 960 blocks, 256 threads ----
// Block emits 2 patch rows (pi0, pi0+1): stages 6 img rows of 16 ch (strip-
// summed, pre-scaled), then LUT-driven emit. 3 staged rows per emitted row
// (vs 5 in r8) -> 40% less staging traffic/instructions.
#define UH   16                      // channels per block
#define NR   6                       // staged img rows (2 patch rows + 4)
#define LJS  68                      // padded j stride (f4-aligned)

__global__ __launch_bounds__(256) void unfold_kernel(const float* __restrict__ slab,
                                                     float* __restrict__ out) {
    __shared__ float li[UH * NR * LJS];        // 16*6*68 = 6528 fl = 26.1 KB
    __shared__ int4 lut[100];                  // 1.6 KB
    const int hh  = blockIdx.x;                // 0..3
    const int piq = blockIdx.y;                // 0..29
    const int im  = blockIdx.z;
    const int t   = threadIdx.x;
    const int h0  = hh * UH;
    const int pi0 = piq * 2;

    if (t < 100) {                             // f4-slot r -> 4 LDS offsets (R*LJS+dj)
        int4 e;
        int* ep = &e.x;
#pragma unroll
        for (int k = 0; k < 4; ++k) {
            int fl = 4 * t + k;                // = ho*25 + v
            int ho = fl / 25, v = fl - 25 * ho;
            int di = v / 5, dj = v - 5 * di;
            ep[k] = (ho * NR + di) * LJS + dj; // row block is NR tall now
        }
        lut[t] = e;
    }

    // stage img rows pi0..pi0+5 of 16 channels (strip-summed), scaled 1/(ci*cj)
    for (int u = t; u < UH * NR * 16; u += 256) {      // 1536
        int ch = u / (NR * 16), rem = u - ch * (NR * 16);
        int dr = rem >> 4, j4 = rem & 15;
        int i = pi0 + dr;                      // <= 63
        int s_hi = min(i / 5, NSTRIP - 1);
        int s_lo = (i <= 8) ? 0 : (i - 4) / 5;
        const float* pa = slab +
            (((size_t)(s_lo * 8 + im) * 64 + h0 + ch) * SROWS + (i - 5 * s_lo)) * 64 + (j4 << 2);
        float4 v = *reinterpret_cast<const float4*>(pa);
        if (s_hi != s_lo) {
            const float* pb = slab +
                (((size_t)(s_hi * 8 + im) * 64 + h0 + ch) * SROWS + (i - 5 * s_hi)) * 64 + (j4 << 2);
            float4 w = *reinterpret_cast<const float4*>(pb);
            v.x += w.x; v.y += w.y; v.z += w.z; v.w += w.w;
        }
        float ri = 1.0f / (float)min(min(i + 1, 64 - i), 5);
        int jb = j4 << 2;
        float4 w;
        w.x = v.x * ri * (1.0f / (float)min(min(jb + 1, 64 - jb), 5));
        w.y = v.y * ri * (1.0f / (float)min(min(jb + 2, 63 - jb), 5));
        w.z = v.z * ri * (1.0f / (float)min(min(jb + 3, 62 - jb), 5));
        w.w = v.w * ri * (1.0f / (float)min(min(jb + 4, 61 - jb), 5));
        *reinterpret_cast<float4*>(&li[(ch * NR + dr) * LJS + jb]) = w;
    }
    __syncthreads();

    // emit: 2 patch rows x 60 pj x 100 f4; patch row pr shifts di window by +pr
    for (int u = t; u < 12000; u += 256) {
        int pr = u / 6000, rem2 = u - 6000 * pr;
        int pj = rem2 / 100, r = rem2 - 100 * pj;
        int4 e = lut[r];
        int sh = pj + pr * LJS;                // +1 row within each NR block
        float4 o;
        o.x = li[e.x + sh];
        o.y = li[e.y + sh];
        o.z = li[e.z + sh];
        o.w = li[e.w + sh];
        float* ob = out + ((size_t)im * NPATCH + (size_t)(pi0 + pr) * OH + pj) * CDIM + h0 * VF;
        *reinterpret_cast<float4*>(ob + 4 * r) = o;
    }
}

extern "C" void kernel_launch(void* const* d_in, const int* in_sizes, int n_in,
                              void* d_out, int out_size, void* d_ws, size_t ws_size,
                              hipStream_t stream) {
    const float* x = (const float*)d_in[0];
    float* slab = (float*)d_ws;                // 12*8*64*9*64 fl = 14.2 MB
    float* out  = (float*)d_out;

    fold_kernel<<<dim3(8, NSTRIP, NIMG), 512, 0, stream>>>(x, slab);     // 768 blocks
    unfold_kernel<<<dim3(4, 30, NIMG), 256, 0, stream>>>(slab, out);     // 960 blocks

    (void)out_size; (void)ws_size; (void)in_sizes; (void)n_in;
}

// Round 13
// 78.739 us; speedup vs baseline: 6.2302x; 1.2536x over previous
//
#include <hip/hip_runtime.h>

// images=8, patches=3600(=60*60), hor_f=64, ver_f=25(=5*5), 64x64 px, k=5
#define OH     60
#define NIMG   8
#define HF     64
#define VF     25
#define NPATCH 3600
#define CDIM   1600                  // HF*VF

typedef float floatx4 __attribute__((ext_vector_type(4)));  // native vec for nt-store

// ---- fold (r8, unchanged): grid (hg 8, strip 12, im 8) = 768 blocks, 512 thr ----
#define FH   8                       // h channels per block
#define FC   (FH * VF)               // 200 c values
#define SPI  5                       // pi rows per strip
#define PJS  64                      // pj stride (XOR-swizzled)
#define NSTRIP 12
#define SROWS  9                     // SPI + 4 halo rows

__global__ __launch_bounds__(512, 6) void fold_kernel(const float* __restrict__ x,
                                                      float* __restrict__ slab) {
    __shared__ float lb[FC * PJS];   // 51.2 KB
    const int hg = blockIdx.x, strip = blockIdx.y, im = blockIdx.z;
    const int t = threadIdx.x;
    const int h0 = hg * FH;
    const int pi0 = strip * SPI;
    const int j = t & 63, g = t >> 6;          // g = local h (0..7)

    float acc[SROWS];
#pragma unroll
    for (int k = 0; k < SROWS; ++k) acc[k] = 0.f;

    const float* xb = x + ((size_t)im * NPATCH + (size_t)pi0 * OH) * CDIM + h0 * VF;

    int off_g[6], off_l[6];
#pragma unroll
    for (int k = 0; k < 6; ++k) {
        int u = t + 512 * k;
        if (u < 3000) {
            int pj = u / 50, c4 = u - 50 * pj;
            off_g[k] = pj * CDIM + (c4 << 2);
            off_l[k] = (c4 << 8) + (pj ^ (c4 & 31));
        }
    }

    float4 stg[6];
#pragma unroll
    for (int k = 0; k < 6; ++k)
        if (t + 512 * k < 3000)
            stg[k] = *reinterpret_cast<const float4*>(xb + off_g[k]);

#pragma unroll
    for (int row = 0; row < SPI; ++row) {
        if (row) __syncthreads();
#pragma unroll
        for (int k = 0; k < 6; ++k)
            if (t + 512 * k < 3000) {
                float4 v = stg[k];
                int a = off_l[k];
                lb[a]           = v.x;
                lb[a + PJS]     = v.y;
                lb[a + 2 * PJS] = v.z;
                lb[a + 3 * PJS] = v.w;
            }
        if (row + 1 < SPI) {                   // prefetch next row during compute
#pragma unroll
            for (int k = 0; k < 6; ++k)
                if (t + 512 * k < 3000)
                    stg[k] = *reinterpret_cast<const float4*>(
                        xb + (size_t)(row + 1) * OH * CDIM + off_g[k]);
        }
        __syncthreads();
#pragma unroll
        for (int di = 0; di < 5; ++di) {
#pragma unroll
            for (int dj = 0; dj < 5; ++dj) {
                int c = g * VF + di * 5 + dj;
                int pjr = j - dj;
                if ((unsigned)pjr < 60u)
                    acc[row + di] += lb[c * PJS + (pjr ^ ((c >> 2) & 31))];
            }
        }
    }

    float* sb = slab + (((size_t)(strip * 8 + im) * 64 + h0 + g) * SROWS) * 64 + j;
#pragma unroll
    for (int il = 0; il < SROWS; ++il) sb[il * 64] = acc[il];
}

// ---- unfold (r8 structure + NT stores): grid (hh 4, pi 60, im 8), 256 thr ----
#define UH   16                      // channels per block
#define LJS  68                      // padded j stride (f4-aligned)

__global__ __launch_bounds__(256) void unfold_kernel(const float* __restrict__ slab,
                                                     float* __restrict__ out) {
    __shared__ float li[UH * 5 * LJS];         // 5440 fl = 21.76 KB
    __shared__ int4 lut[100];
    const int hh = blockIdx.x;                 // 0..3
    const int pi = blockIdx.y;                 // 0..59
    const int im = blockIdx.z;
    const int t = threadIdx.x;
    const int h0 = hh * UH;

    if (t < 100) {                             // f4-slot r -> 4 LDS offsets (R*LJS+dj)
        int4 e;
        int* ep = &e.x;
#pragma unroll
        for (int k = 0; k < 4; ++k) {
            int fl = 4 * t + k;                // = ho*25 + v
            int ho = fl / 25, v = fl - 25 * ho;
            int di = v / 5, dj = v - 5 * di;
            ep[k] = (ho * 5 + di) * LJS + dj;
        }
        lut[t] = e;
    }

    // stage rows pi..pi+4 of 16 channels (strip-summed), pre-scaled by 1/(ci*cj)
    for (int u = t; u < UH * 5 * 16; u += 256) {
        int ch = u / 80, rem = u - 80 * ch;
        int di = rem >> 4, j4 = rem & 15;
        int i = pi + di;
        int s_hi = min(i / 5, NSTRIP - 1);
        int s_lo = (i <= 8) ? 0 : (i - 4) / 5;
        const float* pa = slab +
            (((size_t)(s_lo * 8 + im) * 64 + h0 + ch) * SROWS + (i - 5 * s_lo)) * 64 + (j4 << 2);
        float4 v = *reinterpret_cast<const float4*>(pa);
        if (s_hi != s_lo) {
            const float* pb = slab +
                (((size_t)(s_hi * 8 + im) * 64 + h0 + ch) * SROWS + (i - 5 * s_hi)) * 64 + (j4 << 2);
            float4 w = *reinterpret_cast<const float4*>(pb);
            v.x += w.x; v.y += w.y; v.z += w.z; v.w += w.w;
        }
        float ri = 1.0f / (float)min(min(i + 1, 64 - i), 5);
        int jb = j4 << 2;
        float4 w;
        w.x = v.x * ri * (1.0f / (float)min(min(jb + 1, 64 - jb), 5));
        w.y = v.y * ri * (1.0f / (float)min(min(jb + 2, 63 - jb), 5));
        w.z = v.z * ri * (1.0f / (float)min(min(jb + 3, 62 - jb), 5));
        w.w = v.w * ri * (1.0f / (float)min(min(jb + 4, 61 - jb), 5));
        *reinterpret_cast<float4*>(&li[(ch * 5 + di) * LJS + jb]) = w;
    }
    __syncthreads();

    // emit: 60 pj x 100 float4, LUT-addressed, NON-TEMPORAL coalesced writes.
    // nt: out is never re-read; keep it out of L2/L3 so x + slab stay resident
    // across timed replays (382 MB working set > 256 MB L3 without this).
    float* ob = out + ((size_t)im * NPATCH + (size_t)pi * OH) * CDIM + h0 * VF;
    for (int u = t; u < 6000; u += 256) {
        int pj = u / 100, r = u - 100 * pj;
        int4 e = lut[r];
        floatx4 o;
        o.x = li[e.x + pj];
        o.y = li[e.y + pj];
        o.z = li[e.z + pj];
        o.w = li[e.w + pj];
        __builtin_nontemporal_store(o,
            reinterpret_cast<floatx4*>(ob + (size_t)pj * CDIM + 4 * r));
    }
}

extern "C" void kernel_launch(void* const* d_in, const int* in_sizes, int n_in,
                              void* d_out, int out_size, void* d_ws, size_t ws_size,
                              hipStream_t stream) {
    const float* x = (const float*)d_in[0];
    float* slab = (float*)d_ws;                // 12*8*64*9*64 fl = 14.2 MB
    float* out  = (float*)d_out;

    fold_kernel<<<dim3(8, NSTRIP, NIMG), 512, 0, stream>>>(x, slab);   // 768 blocks
    unfold_kernel<<<dim3(4, OH, NIMG), 256, 0, stream>>>(slab, out);   // 1920 blocks

    (void)out_size; (void)ws_size; (void)in_sizes; (void)n_in;
}